// Round 19
// baseline (1560.465 us; speedup 1.0000x reference)
//
#include <hip/hip_runtime.h>
#include <hip/hip_bf16.h>
#include <cstdint>
#include <cstddef>

#define NN 16000
#define MPAD 16128
#define EE 256000
#define ETOT (EE + NN)
#define RREL 8
#define NHEAD 8
#define DOUT 64
#define HD 512
#define NEG 0.2f
#define NMAIN 1008
#define NQK 63
#define NSCAT 532  // scatter tail blocks (512 threads each)
#define NBH 1063   // hist blocks
#define NBA 4000   // asplit L1 blocks
#define NBW1 129   // wqk L1 blocks (128 + cvec)
#define NBB1 256   // bsplit L1 blocks
#define NBATT 4000 // attn blocks
#define NBB2 512   // bsplit L2 blocks
#define NBW2 257   // wqk L2 blocks (256 + cvec)

typedef unsigned int u32;
typedef short bf16x8 __attribute__((ext_vector_type(8)));
typedef float f32x4 __attribute__((ext_vector_type(4)));

// ---------- helpers ----------
__device__ inline unsigned short f2bf(float f) {
  u32 i = __float_as_uint(f);
  u32 r = (i + 0x7fff + ((i >> 16) & 1)) >> 16;  // RNE, finite values
  return (unsigned short)r;
}
__device__ inline float bf2f(unsigned short h) {
  return __uint_as_float((u32)h << 16);
}
__device__ inline void g2lds16(const void* g, void* lds) {
  __builtin_amdgcn_global_load_lds(
      (const __attribute__((address_space(1))) unsigned int*)g,
      (__attribute__((address_space(3))) unsigned int*)lds, 16, 0, 0);
}

// ---------- fused-prep device functions ----------
__device__ __forceinline__ void dev_hist(int bid, const int* __restrict__ ei,
                                         const int* __restrict__ et,
                                         int* __restrict__ deg, int* meta) {
  int e = bid * 256 + (int)threadIdx.x;
  if (e >= ETOT) return;
  int dst;
  if (e < EE) { dst = ei[EE + e]; atomicMax(&meta[0], et[e]); }
  else dst = e - EE;
  atomicAdd(&deg[dst], 1);
}

__device__ __forceinline__ void dev_asplit(int bid, const float* __restrict__ in,
                                           unsigned short* __restrict__ A2, int F) {
  long idx = (long)bid * 256 + threadIdx.x;
  long total = (long)NN * (F >> 2);
  if (idx >= total) return;
  int row = (int)(idx / (F >> 2));
  int c4 = (int)(idx % (F >> 2)) << 2;
  float4 v = *(const float4*)&in[(size_t)row * F + c4];
  ushort4 hi;
  hi.x = f2bf(v.x); hi.y = f2bf(v.y); hi.z = f2bf(v.z); hi.w = f2bf(v.w);
  *(ushort4*)&A2[(size_t)row * F + c4] = hi;
}

__device__ __forceinline__ void dev_wqk(int bid, int nmain, const float* __restrict__ W,
                                        const float* __restrict__ q,
                                        const float* __restrict__ k,
                                        const float* __restrict__ We,
                                        const float* __restrict__ e,
                                        unsigned short* __restrict__ WQKT,
                                        float* __restrict__ cvec, int F) {
  if (bid == nmain) {
    int j = threadIdx.x;
    if (j < NHEAD) {
      float acc = 0.f;
      for (int h2 = 0; h2 < HD; ++h2) acc += We[h2] * e[h2 * NHEAD + j];
      cvec[j] = acc;
    }
    return;
  }
  int g = bid * 256 + (int)threadIdx.x;
  int j = g & 15;
  int rf = g >> 4;  // r*F + f
  int f = rf % F;
  const float* wrow = W + (size_t)rf * HD;
  const float* qk = ((j < 8) ? q : k) + (j & 7);
  float acc = 0.f;
  for (int h = 0; h < HD; ++h) acc += wrow[h] * qk[(size_t)h * NHEAD];
  const int col = (rf / F) * 16 + j;
  WQKT[(size_t)col * F + f] = f2bf(acc);
}

__device__ void dev_bsplit(int f0b, int c0b, int r, const float* __restrict__ W,
                           unsigned short* __restrict__ BT, int F,
                           float (*tile)[65]) {
  const int f0 = f0b * 64, c0 = c0b * 64;
  int tid = threadIdx.x;
  int i0 = tid >> 6;
  int j = tid & 63;
  const float* Wr = W + (size_t)r * F * 512;
  for (int i = i0; i < 64; i += 4)
    tile[i][j] = Wr[(size_t)(f0 + i) * 512 + c0 + j];
  __syncthreads();
  unsigned short* Br = BT + (size_t)r * 512 * F;
  for (int c = i0; c < 64; c += 4) {
    float v = tile[j][c];
    Br[(size_t)(c0 + c) * F + f0 + j] = f2bf(v);
  }
}

// ---------- attn core (CONCAT=1, no LDS): one wave per node -------------
__device__ __forceinline__ void dev_attn1(int bid, const unsigned short* __restrict__ t,
    const float* __restrict__ qkbuf, const float* __restrict__ cvec,
    const int* __restrict__ rowptr, const int* __restrict__ csr_src,
    const int* __restrict__ csr_et, const float* __restrict__ csr_ea,
    const float* __restrict__ bias, unsigned short* __restrict__ A2out) {
  const int wv = threadIdx.x >> 6;
  const int lane = threadIdx.x & 63;
  const int n = bid * 4 + wv;
  const int h = lane >> 3;
  const int c0 = lane << 3;
  const int e0 = rowptr[n], e1 = rowptr[n + 1];
  const float ch = cvec[h];
  const float* qrow = qkbuf + (size_t)n * 128;
  float m = -1e30f, l = 0.f;
  float acc[8] = {};
  int rN = csr_et[e0];
  float aN = csr_ea[e0];
  int sN = csr_src[e0];
  uint4 tvN = *(const uint4*)&t[((size_t)rN * MPAD + sN) * HD + c0];
  float klogN = qkbuf[(size_t)sN * 128 + rN * 16 + 8 + h];
  for (int e = e0; e < e1; ++e) {
    const int r = rN;
    const float a = aN;
    const uint4 tv = tvN;
    const float klog = klogN;
    const float qv = qrow[r * 16 + h];
    if (e + 1 < e1) {
      const int s2 = csr_src[e + 1];
      rN = csr_et[e + 1];
      aN = csr_ea[e + 1];
      tvN = *(const uint4*)&t[((size_t)rN * MPAD + s2) * HD + c0];
      klogN = qkbuf[(size_t)s2 * 128 + rN * 16 + 8 + h];
    }
    float logit = qv + klog + a * ch;
    logit = (logit > 0.f) ? logit : NEG * logit;
    float p;
    if (logit <= m) {
      p = __expf(logit - m);
    } else {
      const float sc = __expf(m - logit);
      l *= sc;
#pragma unroll
      for (int c = 0; c < 8; ++c) acc[c] *= sc;
      m = logit;
      p = 1.f;
    }
    l += p;
    acc[0] = fmaf(p, __uint_as_float((tv.x & 0xffffu) << 16), acc[0]);
    acc[1] = fmaf(p, __uint_as_float(tv.x & 0xffff0000u), acc[1]);
    acc[2] = fmaf(p, __uint_as_float((tv.y & 0xffffu) << 16), acc[2]);
    acc[3] = fmaf(p, __uint_as_float(tv.y & 0xffff0000u), acc[3]);
    acc[4] = fmaf(p, __uint_as_float((tv.z & 0xffffu) << 16), acc[4]);
    acc[5] = fmaf(p, __uint_as_float(tv.z & 0xffff0000u), acc[5]);
    acc[6] = fmaf(p, __uint_as_float((tv.w & 0xffffu) << 16), acc[6]);
    acc[7] = fmaf(p, __uint_as_float(tv.w & 0xffff0000u), acc[7]);
  }
  const float inv = 1.f / (l + 1e-16f);
  unsigned short his[8];
#pragma unroll
  for (int c = 0; c < 8; ++c)
    his[c] = f2bf(fmaf(acc[c], inv, bias[c0 + c]));
  uint4 wh;
  wh.x = (u32)his[0] | ((u32)his[1] << 16);
  wh.y = (u32)his[2] | ((u32)his[3] << 16);
  wh.z = (u32)his[4] | ((u32)his[5] << 16);
  wh.w = (u32)his[6] | ((u32)his[7] << 16);
  *(uint4*)&A2out[(size_t)n * 512 + c0] = wh;
}

// ---------- fused kernel A: hist | asplit(x) | wqk1 | bsplit1 -----------
__global__ __launch_bounds__(256) void k_prep1(const int* __restrict__ ei,
    const int* __restrict__ et, int* __restrict__ deg, int* meta,
    const float* __restrict__ x, unsigned short* __restrict__ A2,
    const float* __restrict__ W1, const float* __restrict__ q1,
    const float* __restrict__ k1, const float* __restrict__ We1,
    const float* __restrict__ e1, unsigned short* __restrict__ WQKT,
    float* __restrict__ cvec1, unsigned short* __restrict__ BT) {
  __shared__ float tile[64][65];
  int b = blockIdx.x;
  if (b < NBH) { dev_hist(b, ei, et, deg, meta); return; }
  b -= NBH;
  if (b < NBA) { dev_asplit(b, x, A2, 256); return; }
  b -= NBA;
  if (b < NBW1) { dev_wqk(b, NBW1 - 1, W1, q1, k1, We1, e1, WQKT, cvec1, 256); return; }
  b -= NBW1;
  dev_bsplit(b & 3, (b >> 2) & 7, b >> 5, W1, BT, 256, tile);
}

// ---------- fused kernel D: attn1 | bsplit2 | wqk2 ----------------------
__global__ __launch_bounds__(256) void k_attn1f(const unsigned short* __restrict__ t,
    const float* __restrict__ qkbuf, const float* __restrict__ cvec1,
    const int* __restrict__ rowptr, const int* __restrict__ csr_src,
    const int* __restrict__ csr_et, const float* __restrict__ csr_ea,
    const float* __restrict__ b1, unsigned short* __restrict__ A2out,
    const float* __restrict__ W2, const float* __restrict__ q2,
    const float* __restrict__ k2, const float* __restrict__ We2,
    const float* __restrict__ e2, unsigned short* __restrict__ WQKT,
    float* __restrict__ cvec2, unsigned short* __restrict__ BT) {
  __shared__ float tile[64][65];
  int b = blockIdx.x;
  if (b < NBATT) {
    dev_attn1(b, t, qkbuf, cvec1, rowptr, csr_src, csr_et, csr_ea, b1, A2out);
    return;
  }
  b -= NBATT;
  if (b < NBB2) { dev_bsplit(b & 7, (b >> 3) & 7, b >> 6, W2, BT, 512, tile); return; }
  b -= NBB2;
  dev_wqk(b, NBW2 - 1, W2, q2, k2, We2, e2, WQKT, cvec2, 512);
}

// ---------- scan (unchanged) --------------------------------------------
__global__ __launch_bounds__(1024) void k_scan(const int* __restrict__ deg,
                                               int* __restrict__ rowptr,
                                               int* __restrict__ fill) {
  __shared__ int sm[1024];
  const int tid = threadIdx.x;
  const int base = tid * 16;
  int local[16];
  int s = 0;
#pragma unroll
  for (int i = 0; i < 16; ++i) {
    int idx = base + i;
    int v = (idx < NN) ? deg[idx] : 0;
    local[i] = s;
    s += v;
  }
  sm[tid] = s;
  __syncthreads();
  for (int off = 1; off < 1024; off <<= 1) {
    int t = (tid >= off) ? sm[tid - off] : 0;
    __syncthreads();
    sm[tid] += t;
    __syncthreads();
  }
  const int pre = (tid > 0) ? sm[tid - 1] : 0;
#pragma unroll
  for (int i = 0; i < 16; ++i) {
    int idx = base + i;
    if (idx < NN) { rowptr[idx] = pre + local[i]; fill[idx] = pre + local[i]; }
  }
  if (tid == 1023) rowptr[NN] = sm[1023];
}

// ---------- MFMA GEMM: 2-buffer 64 KB -> 2 blocks/CU --------------------
// bid < NMAIN: C = A2 @ BT^T (t output). NMAIN..NMAIN+62: qkbuf blocks.
// bid >= NMAIN+63 (layer-1 grid only): scatter tail blocks (512 thr each).
// 256x256 tile, BK=32, 8 waves, 2 LDS buffers (64 KB): per iter
// {vmcnt(0), barrier, issue next-tile stage, 12 ds_read, 32 MFMA}.
// Cross-block overlap (2 blocks/CU) hides the drain.
__global__ __launch_bounds__(512, 4) void k_mgemm(const unsigned short* __restrict__ A2,
                                                  const unsigned short* __restrict__ BT,
                                                  const unsigned short* __restrict__ WQKT,
                                                  unsigned short* __restrict__ Ct,
                                                  float* __restrict__ qkbuf,
                                                  int Kp,
                                                  const int* __restrict__ ei,
                                                  const int* __restrict__ et,
                                                  const float* __restrict__ ea,
                                                  const int* __restrict__ meta,
                                                  int* __restrict__ fill,
                                                  int* __restrict__ csr_src,
                                                  int* __restrict__ csr_et,
                                                  float* __restrict__ csr_ea) {
  const int bid = blockIdx.x;
  if (bid >= NMAIN + NQK) {
    // scatter tail (layer-1 only)
    int e = (bid - NMAIN - NQK) * 512 + (int)threadIdx.x;
    if (e >= ETOT) return;
    int src, dst, r; float a;
    if (e < EE) { src = ei[e]; dst = ei[EE + e]; r = et[e]; a = ea[e]; }
    else { src = dst = e - EE; r = (meta[0] + 1) & (RREL - 1); a = 0.5f; }
    int pos = atomicAdd(&fill[dst], 1);
    csr_src[pos] = src; csr_et[pos] = r; csr_ea[pos] = a;
    return;
  }
  const bool isqk = (bid >= NMAIN);
  int m0, n0;
  const unsigned short* Bbase;
  if (!isqk) {
    const int v = (bid & 7) * 126 + (bid >> 3);   // 1008 = 8*126, bijective
    m0 = (v >> 4) << 8;
    n0 = (v & 15) << 8;
    Bbase = BT;
  } else {
    m0 = (bid - NMAIN) << 8;
    n0 = 0;
    Bbase = WQKT;
  }

  __shared__ __align__(16) unsigned short smem[32768];  // 64 KB
  // A: buf b at [b*8192]; B: at [16384 + b*8192]

  const int tid = threadIdx.x;
  const int wid = tid >> 6;
  const int lane = tid & 63;
  const int wr = wid >> 2;
  const int wc = wid & 3;
  const int rlow = lane & 15;
  const int kch = lane >> 4;

  const unsigned short* srcA[2];
  const unsigned short* srcB[2];
  int dstOff[2];
#pragma unroll
  for (int p = 0; p < 2; ++p) {
    int fr = (p << 3) + wid;
    srcA[p] = A2 + (size_t)(m0 + fr * 16 + rlow) * Kp + kch * 8;
    srcB[p] = Bbase + (size_t)(n0 + fr * 16 + rlow) * Kp + kch * 8;
    dstOff[p] = fr * 512;
  }

  f32x4 acc[8][4] = {};
  const int nt = Kp >> 5;

  // prologue: stage tile 0 into buffer 0
#pragma unroll
  for (int p = 0; p < 2; ++p) {
    g2lds16(srcA[p], &smem[dstOff[p]]);
    g2lds16(srcB[p], &smem[16384 + dstOff[p]]);
  }

  for (int u = 0; u < nt; ++u) {
    asm volatile("s_waitcnt vmcnt(0)" ::: "memory");
    __builtin_amdgcn_s_barrier();
    asm volatile("" ::: "memory");
    const int buf = u & 1;
    if (u + 1 < nt) {
      const int ko = (u + 1) << 5;
      const int bo = (buf ^ 1) * 8192;
#pragma unroll
      for (int p = 0; p < 2; ++p) {
        g2lds16(srcA[p] + ko, &smem[bo + dstOff[p]]);
        g2lds16(srcB[p] + ko, &smem[16384 + bo + dstOff[p]]);
      }
    }
    const unsigned short* Ab = smem + buf * 8192;
    const unsigned short* Bb = smem + 16384 + buf * 8192;
    bf16x8 af[8], bv[4];
#pragma unroll
    for (int i = 0; i < 8; ++i)
      af[i] = *(const bf16x8*)&Ab[(wr * 8 + i) * 512 + lane * 8];
#pragma unroll
    for (int j = 0; j < 4; ++j)
      bv[j] = *(const bf16x8*)&Bb[(wc * 4 + j) * 512 + lane * 8];
    __builtin_amdgcn_s_setprio(1);
#pragma unroll
    for (int i = 0; i < 8; ++i)
#pragma unroll
      for (int j = 0; j < 4; ++j)
        acc[i][j] = __builtin_amdgcn_mfma_f32_16x16x32_bf16(af[i], bv[j],
                                                            acc[i][j], 0, 0, 0);
    __builtin_amdgcn_s_setprio(0);
  }

  if (!isqk) {
    __syncthreads();
    float* epsW = (float*)smem + wid * 1344;  // 43 KB total, fits 64 KB
    const int rowL = lane & 15;
    const int cseg = lane >> 4;
    const int colfull0 = n0 + wc * 64;
    const int rr = colfull0 >> 9;
    const int hbase = (colfull0 & 511) + cseg * 16;
#pragma unroll
    for (int i = 0; i < 8; ++i) {
#pragma unroll
      for (int j = 0; j < 4; ++j)
        *(f32x4*)&epsW[(j * 16 + rlow) * 21 + kch * 4] = acc[i][j];
      float vals[16];
#pragma unroll
      for (int c = 0; c < 16; ++c) vals[c] = epsW[(cseg * 16 + c) * 21 + rowL];
      const int rowg = m0 + wr * 128 + i * 16 + rowL;
      unsigned short* dst = Ct + ((size_t)rr * MPAD + rowg) * HD + hbase;
      uint4 w0, w1;
      w0.x = (u32)f2bf(vals[0])  | ((u32)f2bf(vals[1])  << 16);
      w0.y = (u32)f2bf(vals[2])  | ((u32)f2bf(vals[3])  << 16);
      w0.z = (u32)f2bf(vals[4])  | ((u32)f2bf(vals[5])  << 16);
      w0.w = (u32)f2bf(vals[6])  | ((u32)f2bf(vals[7])  << 16);
      w1.x = (u32)f2bf(vals[8])  | ((u32)f2bf(vals[9])  << 16);
      w1.y = (u32)f2bf(vals[10]) | ((u32)f2bf(vals[11]) << 16);
      w1.z = (u32)f2bf(vals[12]) | ((u32)f2bf(vals[13]) << 16);
      w1.w = (u32)f2bf(vals[14]) | ((u32)f2bf(vals[15]) << 16);
      *(uint4*)dst = w0;
      *(uint4*)(dst + 8) = w1;
    }
  } else {
    if (wc < 2) {
#pragma unroll
      for (int i = 0; i < 8; ++i) {
        const int row0 = m0 + wr * 128 + i * 16 + kch * 4;
#pragma unroll
        for (int j = 0; j < 4; ++j) {
          const int col = wc * 64 + j * 16 + rlow;
#pragma unroll
          for (int q = 0; q < 4; ++q) {
            const int row = row0 + q;
            if (row < NN) qkbuf[(size_t)row * 128 + col] = acc[i][j][q];
          }
        }
      }
    }
  }
}

// ---------- final attention (CONCAT=0), standalone ----------------------
__global__ __launch_bounds__(256) void k_attn0(const unsigned short* __restrict__ t,
    const float* __restrict__ qkbuf, const float* __restrict__ cvec,
    const int* __restrict__ rowptr, const int* __restrict__ csr_src,
    const int* __restrict__ csr_et, const float* __restrict__ csr_ea,
    const float* __restrict__ bias, float* __restrict__ out) {
  const int wv = threadIdx.x >> 6;
  const int lane = threadIdx.x & 63;
  const int n = blockIdx.x * 4 + wv;
  const int h = lane >> 3;
  const int c0 = lane << 3;
  const int e0 = rowptr[n], e1 = rowptr[n + 1];
  const float ch = cvec[h];
  const float* qrow = qkbuf + (size_t)n * 128;
  float m = -1e30f, l = 0.f;
  float acc[8] = {};
  int rN = csr_et[e0];
  float aN = csr_ea[e0];
  int sN = csr_src[e0];
  uint4 tvN = *(const uint4*)&t[((size_t)rN * MPAD + sN) * HD + c0];
  float klogN = qkbuf[(size_t)sN * 128 + rN * 16 + 8 + h];
  for (int e = e0; e < e1; ++e) {
    const int r = rN;
    const float a = aN;
    const uint4 tv = tvN;
    const float klog = klogN;
    const float qv = qrow[r * 16 + h];
    if (e + 1 < e1) {
      const int s2 = csr_src[e + 1];
      rN = csr_et[e + 1];
      aN = csr_ea[e + 1];
      tvN = *(const uint4*)&t[((size_t)rN * MPAD + s2) * HD + c0];
      klogN = qkbuf[(size_t)s2 * 128 + rN * 16 + 8 + h];
    }
    float logit = qv + klog + a * ch;
    logit = (logit > 0.f) ? logit : NEG * logit;
    float p;
    if (logit <= m) {
      p = __expf(logit - m);
    } else {
      const float sc = __expf(m - logit);
      l *= sc;
#pragma unroll
      for (int c = 0; c < 8; ++c) acc[c] *= sc;
      m = logit;
      p = 1.f;
    }
    l += p;
    acc[0] = fmaf(p, __uint_as_float((tv.x & 0xffffu) << 16), acc[0]);
    acc[1] = fmaf(p, __uint_as_float(tv.x & 0xffff0000u), acc[1]);
    acc[2] = fmaf(p, __uint_as_float((tv.y & 0xffffu) << 16), acc[2]);
    acc[3] = fmaf(p, __uint_as_float(tv.y & 0xffff0000u), acc[3]);
    acc[4] = fmaf(p, __uint_as_float((tv.z & 0xffffu) << 16), acc[4]);
    acc[5] = fmaf(p, __uint_as_float(tv.z & 0xffff0000u), acc[5]);
    acc[6] = fmaf(p, __uint_as_float((tv.w & 0xffffu) << 16), acc[6]);
    acc[7] = fmaf(p, __uint_as_float(tv.w & 0xffff0000u), acc[7]);
  }
  const float inv = 1.f / (l + 1e-16f);
  __shared__ float sm[4][HD];
#pragma unroll
  for (int c = 0; c < 8; ++c) sm[wv][c0 + c] = acc[c] * inv;
  __syncthreads();
  const int d = lane;
  float s = 0.f;
#pragma unroll
  for (int hh = 0; hh < NHEAD; ++hh) s += sm[wv][hh * 64 + d];
  out[(size_t)n * DOUT + d] = s * 0.125f + bias[d];
}

// ---------- launch ----------
extern "C" void kernel_launch(void* const* d_in, const int* in_sizes, int n_in,
                              void* d_out, int out_size, void* d_ws, size_t ws_size,
                              hipStream_t stream) {
  const float* x   = (const float*)d_in[0];
  const int*   ei  = (const int*)d_in[1];
  const int*   et  = (const int*)d_in[2];
  const float* ea  = (const float*)d_in[3];
  const float* W1  = (const float*)d_in[4];
  const float* q1  = (const float*)d_in[5];
  const float* k1  = (const float*)d_in[6];
  const float* We1 = (const float*)d_in[7];
  const float* e1  = (const float*)d_in[8];
  const float* b1  = (const float*)d_in[9];
  const float* W2  = (const float*)d_in[10];
  const float* q2  = (const float*)d_in[11];
  const float* k2  = (const float*)d_in[12];
  const float* We2 = (const float*)d_in[13];
  const float* e2  = (const float*)d_in[14];
  const float* b2  = (const float*)d_in[15];
  float* out = (float*)d_out;

  char* w = (char*)d_ws;
  auto alloc = [&](size_t bytes) {
    char* p = w;
    w += (bytes + 255) & ~(size_t)255;
    return p;
  };
  float* qkbuf  = (float*)alloc((size_t)NN * 128 * 4);
  unsigned short* WQKT = (unsigned short*)alloc((size_t)256 * HD * 2);
  unsigned short* A2 = (unsigned short*)alloc((size_t)MPAD * HD * 2);
  unsigned short* BT = (unsigned short*)alloc((size_t)RREL * HD * HD * 2);
  float* cvec1  = (float*)alloc(64);
  float* cvec2  = (float*)alloc(64);
  int*   meta   = (int*)alloc(64);
  int*   deg    = (int*)alloc((size_t)NN * 4);
  int*   rowptr = (int*)alloc((size_t)(NN + 1) * 4);
  int*   fill   = (int*)alloc((size_t)NN * 4);
  int*   csr_src= (int*)alloc((size_t)ETOT * 4);
  int*   csr_et = (int*)alloc((size_t)ETOT * 4);
  float* csr_ea = (float*)alloc((size_t)ETOT * 4);
  unsigned short* t = (unsigned short*)alloc((size_t)RREL * MPAD * HD * 2);
  (void)ws_size;

  (void)hipMemsetAsync(meta, 0, 4, stream);
  (void)hipMemsetAsync(deg, 0, (size_t)NN * 4, stream);
  // A: hist | asplit | wqk1 | bsplit1
  k_prep1<<<NBH + NBA + NBW1 + NBB1, 256, 0, stream>>>(
      ei, et, deg, meta, x, A2, W1, q1, k1, We1, e1, WQKT, cvec1, BT);
  k_scan<<<1, 1024, 0, stream>>>(deg, rowptr, fill);
  // layer 1 GEMM (Kp=256) + qk tail + scatter tail
  k_mgemm<<<NMAIN + NQK + NSCAT, 512, 0, stream>>>(
      A2, BT, WQKT, t, qkbuf, 256, ei, et, ea, meta, fill,
      csr_src, csr_et, csr_ea);
  // D: attn1 (writes A2, stride 512) | bsplit2 | wqk2
  k_attn1f<<<NBATT + NBB2 + NBW2, 256, 0, stream>>>(
      t, qkbuf, cvec1, rowptr, csr_src, csr_et, csr_ea, b1, A2,
      W2, q2, k2, We2, e2, WQKT, cvec2, BT);
  // layer 2 GEMM (Kp=512) + qk tail (no scatter)
  k_mgemm<<<NMAIN + NQK, 512, 0, stream>>>(
      A2, BT, WQKT, t, qkbuf, 512, ei, et, ea, meta, fill,
      csr_src, csr_et, csr_ea);
  k_attn0<<<NN / 4, 256, 0, stream>>>(t, qkbuf, cvec2, rowptr, csr_src, csr_et,
                                      csr_ea, b2, out);
}

// Round 20
// 456.314 us; speedup vs baseline: 3.4197x; 3.4197x over previous
//
#include <hip/hip_runtime.h>
#include <hip/hip_bf16.h>
#include <cstdint>
#include <cstddef>

#define NN 16000
#define MPAD 16128
#define EE 256000
#define ETOT (EE + NN)
#define RREL 8
#define NHEAD 8
#define DOUT 64
#define HD 512
#define NEG 0.2f
#define NMAIN 1008
#define NQK 63
#define NSCAT 532  // scatter tail blocks (512 threads each)
#define NBH 1063   // hist blocks
#define NBA 4000   // asplit L1 blocks
#define NBW1 129   // wqk L1 blocks (128 + cvec)
#define NBB1 256   // bsplit L1 blocks
#define NBATT 4000 // attn blocks
#define NBB2 512   // bsplit L2 blocks
#define NBW2 257   // wqk L2 blocks (256 + cvec)

typedef unsigned int u32;
typedef short bf16x8 __attribute__((ext_vector_type(8)));
typedef float f32x4 __attribute__((ext_vector_type(4)));

// ---------- helpers ----------
__device__ inline unsigned short f2bf(float f) {
  u32 i = __float_as_uint(f);
  u32 r = (i + 0x7fff + ((i >> 16) & 1)) >> 16;  // RNE, finite values
  return (unsigned short)r;
}
__device__ inline float bf2f(unsigned short h) {
  return __uint_as_float((u32)h << 16);
}
__device__ inline void g2lds16(const void* g, void* lds) {
  __builtin_amdgcn_global_load_lds(
      (const __attribute__((address_space(1))) unsigned int*)g,
      (__attribute__((address_space(3))) unsigned int*)lds, 16, 0, 0);
}

// ---------- fused-prep device functions ----------
__device__ __forceinline__ void dev_hist(int bid, const int* __restrict__ ei,
                                         const int* __restrict__ et,
                                         int* __restrict__ deg, int* meta) {
  int e = bid * 256 + (int)threadIdx.x;
  if (e >= ETOT) return;
  int dst;
  if (e < EE) { dst = ei[EE + e]; atomicMax(&meta[0], et[e]); }
  else dst = e - EE;
  atomicAdd(&deg[dst], 1);
}

__device__ __forceinline__ void dev_asplit(int bid, const float* __restrict__ in,
                                           unsigned short* __restrict__ A2, int F) {
  long idx = (long)bid * 256 + threadIdx.x;
  long total = (long)NN * (F >> 2);
  if (idx >= total) return;
  int row = (int)(idx / (F >> 2));
  int c4 = (int)(idx % (F >> 2)) << 2;
  float4 v = *(const float4*)&in[(size_t)row * F + c4];
  ushort4 hi;
  hi.x = f2bf(v.x); hi.y = f2bf(v.y); hi.z = f2bf(v.z); hi.w = f2bf(v.w);
  *(ushort4*)&A2[(size_t)row * F + c4] = hi;
}

__device__ __forceinline__ void dev_wqk(int bid, int nmain, const float* __restrict__ W,
                                        const float* __restrict__ q,
                                        const float* __restrict__ k,
                                        const float* __restrict__ We,
                                        const float* __restrict__ e,
                                        unsigned short* __restrict__ WQKT,
                                        float* __restrict__ cvec, int F) {
  if (bid == nmain) {
    int j = threadIdx.x;
    if (j < NHEAD) {
      float acc = 0.f;
      for (int h2 = 0; h2 < HD; ++h2) acc += We[h2] * e[h2 * NHEAD + j];
      cvec[j] = acc;
    }
    return;
  }
  int g = bid * 256 + (int)threadIdx.x;
  int j = g & 15;
  int rf = g >> 4;  // r*F + f
  int f = rf % F;
  const float* wrow = W + (size_t)rf * HD;
  const float* qk = ((j < 8) ? q : k) + (j & 7);
  float acc = 0.f;
  for (int h = 0; h < HD; ++h) acc += wrow[h] * qk[(size_t)h * NHEAD];
  const int col = (rf / F) * 16 + j;
  WQKT[(size_t)col * F + f] = f2bf(acc);
}

__device__ void dev_bsplit(int f0b, int c0b, int r, const float* __restrict__ W,
                           unsigned short* __restrict__ BT, int F,
                           float (*tile)[65]) {
  const int f0 = f0b * 64, c0 = c0b * 64;
  int tid = threadIdx.x;
  int i0 = tid >> 6;
  int j = tid & 63;
  const float* Wr = W + (size_t)r * F * 512;
  for (int i = i0; i < 64; i += 4)
    tile[i][j] = Wr[(size_t)(f0 + i) * 512 + c0 + j];
  __syncthreads();
  unsigned short* Br = BT + (size_t)r * 512 * F;
  for (int c = i0; c < 64; c += 4) {
    float v = tile[j][c];
    Br[(size_t)(c0 + c) * F + f0 + j] = f2bf(v);
  }
}

// ---------- attn core (CONCAT=1, no LDS): one wave per node -------------
__device__ __forceinline__ void dev_attn1(int bid, const unsigned short* __restrict__ t,
    const float* __restrict__ qkbuf, const float* __restrict__ cvec,
    const int* __restrict__ rowptr, const int* __restrict__ csr_src,
    const int* __restrict__ csr_et, const float* __restrict__ csr_ea,
    const float* __restrict__ bias, unsigned short* __restrict__ A2out) {
  const int wv = threadIdx.x >> 6;
  const int lane = threadIdx.x & 63;
  const int n = bid * 4 + wv;
  const int h = lane >> 3;
  const int c0 = lane << 3;
  const int e0 = rowptr[n], e1 = rowptr[n + 1];
  const float ch = cvec[h];
  const float* qrow = qkbuf + (size_t)n * 128;
  float m = -1e30f, l = 0.f;
  float acc[8] = {};
  int rN = csr_et[e0];
  float aN = csr_ea[e0];
  int sN = csr_src[e0];
  uint4 tvN = *(const uint4*)&t[((size_t)rN * MPAD + sN) * HD + c0];
  float klogN = qkbuf[(size_t)sN * 128 + rN * 16 + 8 + h];
  for (int e = e0; e < e1; ++e) {
    const int r = rN;
    const float a = aN;
    const uint4 tv = tvN;
    const float klog = klogN;
    const float qv = qrow[r * 16 + h];
    if (e + 1 < e1) {
      const int s2 = csr_src[e + 1];
      rN = csr_et[e + 1];
      aN = csr_ea[e + 1];
      tvN = *(const uint4*)&t[((size_t)rN * MPAD + s2) * HD + c0];
      klogN = qkbuf[(size_t)s2 * 128 + rN * 16 + 8 + h];
    }
    float logit = qv + klog + a * ch;
    logit = (logit > 0.f) ? logit : NEG * logit;
    float p;
    if (logit <= m) {
      p = __expf(logit - m);
    } else {
      const float sc = __expf(m - logit);
      l *= sc;
#pragma unroll
      for (int c = 0; c < 8; ++c) acc[c] *= sc;
      m = logit;
      p = 1.f;
    }
    l += p;
    acc[0] = fmaf(p, __uint_as_float((tv.x & 0xffffu) << 16), acc[0]);
    acc[1] = fmaf(p, __uint_as_float(tv.x & 0xffff0000u), acc[1]);
    acc[2] = fmaf(p, __uint_as_float((tv.y & 0xffffu) << 16), acc[2]);
    acc[3] = fmaf(p, __uint_as_float(tv.y & 0xffff0000u), acc[3]);
    acc[4] = fmaf(p, __uint_as_float((tv.z & 0xffffu) << 16), acc[4]);
    acc[5] = fmaf(p, __uint_as_float(tv.z & 0xffff0000u), acc[5]);
    acc[6] = fmaf(p, __uint_as_float((tv.w & 0xffffu) << 16), acc[6]);
    acc[7] = fmaf(p, __uint_as_float(tv.w & 0xffff0000u), acc[7]);
  }
  const float inv = 1.f / (l + 1e-16f);
  unsigned short his[8];
#pragma unroll
  for (int c = 0; c < 8; ++c)
    his[c] = f2bf(fmaf(acc[c], inv, bias[c0 + c]));
  uint4 wh;
  wh.x = (u32)his[0] | ((u32)his[1] << 16);
  wh.y = (u32)his[2] | ((u32)his[3] << 16);
  wh.z = (u32)his[4] | ((u32)his[5] << 16);
  wh.w = (u32)his[6] | ((u32)his[7] << 16);
  *(uint4*)&A2out[(size_t)n * 512 + c0] = wh;
}

// ---------- fused kernel A: hist | asplit(x) | wqk1 | bsplit1 -----------
__global__ __launch_bounds__(256) void k_prep1(const int* __restrict__ ei,
    const int* __restrict__ et, int* __restrict__ deg, int* meta,
    const float* __restrict__ x, unsigned short* __restrict__ A2,
    const float* __restrict__ W1, const float* __restrict__ q1,
    const float* __restrict__ k1, const float* __restrict__ We1,
    const float* __restrict__ e1, unsigned short* __restrict__ WQKT,
    float* __restrict__ cvec1, unsigned short* __restrict__ BT) {
  __shared__ float tile[64][65];
  int b = blockIdx.x;
  if (b < NBH) { dev_hist(b, ei, et, deg, meta); return; }
  b -= NBH;
  if (b < NBA) { dev_asplit(b, x, A2, 256); return; }
  b -= NBA;
  if (b < NBW1) { dev_wqk(b, NBW1 - 1, W1, q1, k1, We1, e1, WQKT, cvec1, 256); return; }
  b -= NBW1;
  dev_bsplit(b & 3, (b >> 2) & 7, b >> 5, W1, BT, 256, tile);
}

// ---------- fused kernel D: attn1 | bsplit2 | wqk2 ----------------------
__global__ __launch_bounds__(256) void k_attn1f(const unsigned short* __restrict__ t,
    const float* __restrict__ qkbuf, const float* __restrict__ cvec1,
    const int* __restrict__ rowptr, const int* __restrict__ csr_src,
    const int* __restrict__ csr_et, const float* __restrict__ csr_ea,
    const float* __restrict__ b1, unsigned short* __restrict__ A2out,
    const float* __restrict__ W2, const float* __restrict__ q2,
    const float* __restrict__ k2, const float* __restrict__ We2,
    const float* __restrict__ e2, unsigned short* __restrict__ WQKT,
    float* __restrict__ cvec2, unsigned short* __restrict__ BT) {
  __shared__ float tile[64][65];
  int b = blockIdx.x;
  if (b < NBATT) {
    dev_attn1(b, t, qkbuf, cvec1, rowptr, csr_src, csr_et, csr_ea, b1, A2out);
    return;
  }
  b -= NBATT;
  if (b < NBB2) { dev_bsplit(b & 7, (b >> 3) & 7, b >> 6, W2, BT, 512, tile); return; }
  b -= NBB2;
  dev_wqk(b, NBW2 - 1, W2, q2, k2, We2, e2, WQKT, cvec2, 512);
}

// ---------- scan (unchanged) --------------------------------------------
__global__ __launch_bounds__(1024) void k_scan(const int* __restrict__ deg,
                                               int* __restrict__ rowptr,
                                               int* __restrict__ fill) {
  __shared__ int sm[1024];
  const int tid = threadIdx.x;
  const int base = tid * 16;
  int local[16];
  int s = 0;
#pragma unroll
  for (int i = 0; i < 16; ++i) {
    int idx = base + i;
    int v = (idx < NN) ? deg[idx] : 0;
    local[i] = s;
    s += v;
  }
  sm[tid] = s;
  __syncthreads();
  for (int off = 1; off < 1024; off <<= 1) {
    int t = (tid >= off) ? sm[tid - off] : 0;
    __syncthreads();
    sm[tid] += t;
    __syncthreads();
  }
  const int pre = (tid > 0) ? sm[tid - 1] : 0;
#pragma unroll
  for (int i = 0; i < 16; ++i) {
    int idx = base + i;
    if (idx < NN) { rowptr[idx] = pre + local[i]; fill[idx] = pre + local[i]; }
  }
  if (tid == 1023) rowptr[NN] = sm[1023];
}

// ---------- MFMA GEMM (round-17 proven body: 3 buf, 96 KB, vmcnt(4)) ----
// bid < NMAIN: C = A2 @ BT^T (t output). NMAIN..NMAIN+62: qkbuf blocks.
// bid >= NMAIN+63 (layer-1 grid only): scatter tail blocks (512 thr each).
__global__ __launch_bounds__(512, 2) void k_mgemm(const unsigned short* __restrict__ A2,
                                                  const unsigned short* __restrict__ BT,
                                                  const unsigned short* __restrict__ WQKT,
                                                  unsigned short* __restrict__ Ct,
                                                  float* __restrict__ qkbuf,
                                                  int Kp,
                                                  const int* __restrict__ ei,
                                                  const int* __restrict__ et,
                                                  const float* __restrict__ ea,
                                                  const int* __restrict__ meta,
                                                  int* __restrict__ fill,
                                                  int* __restrict__ csr_src,
                                                  int* __restrict__ csr_et,
                                                  float* __restrict__ csr_ea) {
  const int bid = blockIdx.x;
  if (bid >= NMAIN + NQK) {
    // scatter tail (layer-1 only)
    int e = (bid - NMAIN - NQK) * 512 + (int)threadIdx.x;
    if (e >= ETOT) return;
    int src, dst, r; float a;
    if (e < EE) { src = ei[e]; dst = ei[EE + e]; r = et[e]; a = ea[e]; }
    else { src = dst = e - EE; r = (meta[0] + 1) & (RREL - 1); a = 0.5f; }
    int pos = atomicAdd(&fill[dst], 1);
    csr_src[pos] = src; csr_et[pos] = r; csr_ea[pos] = a;
    return;
  }
  const bool isqk = (bid >= NMAIN);
  int m0, n0;
  const unsigned short* Bbase;
  if (!isqk) {
    const int v = (bid & 7) * 126 + (bid >> 3);   // 1008 = 8*126, bijective
    m0 = (v >> 4) << 8;
    n0 = (v & 15) << 8;
    Bbase = BT;
  } else {
    m0 = (bid - NMAIN) << 8;
    n0 = 0;
    Bbase = WQKT;
  }

  __shared__ __align__(16) unsigned short smem[49152];  // 96 KB

  const int tid = threadIdx.x;
  const int wid = tid >> 6;
  const int lane = tid & 63;
  const int wr = wid >> 2;
  const int wc = wid & 3;
  const int rlow = lane & 15;
  const int kch = lane >> 4;

  const unsigned short* srcA[2];
  const unsigned short* srcB[2];
  int dstOff[2];
#pragma unroll
  for (int p = 0; p < 2; ++p) {
    int fr = (p << 3) + wid;
    srcA[p] = A2 + (size_t)(m0 + fr * 16 + rlow) * Kp + kch * 8;
    srcB[p] = Bbase + (size_t)(n0 + fr * 16 + rlow) * Kp + kch * 8;
    dstOff[p] = fr * 512;
  }

  f32x4 acc[8][4] = {};
  const int nt = Kp >> 5;

#pragma unroll
  for (int tp = 0; tp < 2; ++tp) {
    const int ko = tp << 5;
#pragma unroll
    for (int p = 0; p < 2; ++p) {
      g2lds16(srcA[p] + ko, &smem[tp * 8192 + dstOff[p]]);
      g2lds16(srcB[p] + ko, &smem[24576 + tp * 8192 + dstOff[p]]);
    }
  }

  int buf = 0;
  for (int u = 0; u < nt; ++u) {
    if (u + 1 < nt)
      asm volatile("s_waitcnt vmcnt(4)" ::: "memory");
    else
      asm volatile("s_waitcnt vmcnt(0)" ::: "memory");
    __builtin_amdgcn_s_barrier();
    asm volatile("" ::: "memory");
    if (u + 2 < nt) {
      int nb2 = buf + 2; if (nb2 >= 3) nb2 -= 3;
      const int ko = (u + 2) << 5;
#pragma unroll
      for (int p = 0; p < 2; ++p) {
        g2lds16(srcA[p] + ko, &smem[nb2 * 8192 + dstOff[p]]);
        g2lds16(srcB[p] + ko, &smem[24576 + nb2 * 8192 + dstOff[p]]);
      }
    }
    const unsigned short* Ab = smem + buf * 8192;
    const unsigned short* Bb = smem + 24576 + buf * 8192;
    bf16x8 af[8], bv[4];
#pragma unroll
    for (int i = 0; i < 8; ++i)
      af[i] = *(const bf16x8*)&Ab[(wr * 8 + i) * 512 + lane * 8];
#pragma unroll
    for (int j = 0; j < 4; ++j)
      bv[j] = *(const bf16x8*)&Bb[(wc * 4 + j) * 512 + lane * 8];
    __builtin_amdgcn_s_setprio(1);
#pragma unroll
    for (int i = 0; i < 8; ++i)
#pragma unroll
      for (int j = 0; j < 4; ++j)
        acc[i][j] = __builtin_amdgcn_mfma_f32_16x16x32_bf16(af[i], bv[j],
                                                            acc[i][j], 0, 0, 0);
    __builtin_amdgcn_s_setprio(0);
    buf = (buf == 2) ? 0 : buf + 1;
  }

  if (!isqk) {
    __syncthreads();
    float* epsW = (float*)smem + wid * 1344;
    const int rowL = lane & 15;
    const int cseg = lane >> 4;
    const int colfull0 = n0 + wc * 64;
    const int rr = colfull0 >> 9;
    const int hbase = (colfull0 & 511) + cseg * 16;
#pragma unroll
    for (int i = 0; i < 8; ++i) {
#pragma unroll
      for (int j = 0; j < 4; ++j)
        *(f32x4*)&epsW[(j * 16 + rlow) * 21 + kch * 4] = acc[i][j];
      float vals[16];
#pragma unroll
      for (int c = 0; c < 16; ++c) vals[c] = epsW[(cseg * 16 + c) * 21 + rowL];
      const int rowg = m0 + wr * 128 + i * 16 + rowL;
      unsigned short* dst = Ct + ((size_t)rr * MPAD + rowg) * HD + hbase;
      uint4 w0, w1;
      w0.x = (u32)f2bf(vals[0])  | ((u32)f2bf(vals[1])  << 16);
      w0.y = (u32)f2bf(vals[2])  | ((u32)f2bf(vals[3])  << 16);
      w0.z = (u32)f2bf(vals[4])  | ((u32)f2bf(vals[5])  << 16);
      w0.w = (u32)f2bf(vals[6])  | ((u32)f2bf(vals[7])  << 16);
      w1.x = (u32)f2bf(vals[8])  | ((u32)f2bf(vals[9])  << 16);
      w1.y = (u32)f2bf(vals[10]) | ((u32)f2bf(vals[11]) << 16);
      w1.z = (u32)f2bf(vals[12]) | ((u32)f2bf(vals[13]) << 16);
      w1.w = (u32)f2bf(vals[14]) | ((u32)f2bf(vals[15]) << 16);
      *(uint4*)dst = w0;
      *(uint4*)(dst + 8) = w1;
    }
  } else {
    if (wc < 2) {
#pragma unroll
      for (int i = 0; i < 8; ++i) {
        const int row0 = m0 + wr * 128 + i * 16 + kch * 4;
#pragma unroll
        for (int j = 0; j < 4; ++j) {
          const int col = wc * 64 + j * 16 + rlow;
#pragma unroll
          for (int q = 0; q < 4; ++q) {
            const int row = row0 + q;
            if (row < NN) qkbuf[(size_t)row * 128 + col] = acc[i][j][q];
          }
        }
      }
    }
  }
}

// ---------- final attention (CONCAT=0), standalone ----------------------
__global__ __launch_bounds__(256) void k_attn0(const unsigned short* __restrict__ t,
    const float* __restrict__ qkbuf, const float* __restrict__ cvec,
    const int* __restrict__ rowptr, const int* __restrict__ csr_src,
    const int* __restrict__ csr_et, const float* __restrict__ csr_ea,
    const float* __restrict__ bias, float* __restrict__ out) {
  const int wv = threadIdx.x >> 6;
  const int lane = threadIdx.x & 63;
  const int n = blockIdx.x * 4 + wv;
  const int h = lane >> 3;
  const int c0 = lane << 3;
  const int e0 = rowptr[n], e1 = rowptr[n + 1];
  const float ch = cvec[h];
  const float* qrow = qkbuf + (size_t)n * 128;
  float m = -1e30f, l = 0.f;
  float acc[8] = {};
  int rN = csr_et[e0];
  float aN = csr_ea[e0];
  int sN = csr_src[e0];
  uint4 tvN = *(const uint4*)&t[((size_t)rN * MPAD + sN) * HD + c0];
  float klogN = qkbuf[(size_t)sN * 128 + rN * 16 + 8 + h];
  for (int e = e0; e < e1; ++e) {
    const int r = rN;
    const float a = aN;
    const uint4 tv = tvN;
    const float klog = klogN;
    const float qv = qrow[r * 16 + h];
    if (e + 1 < e1) {
      const int s2 = csr_src[e + 1];
      rN = csr_et[e + 1];
      aN = csr_ea[e + 1];
      tvN = *(const uint4*)&t[((size_t)rN * MPAD + s2) * HD + c0];
      klogN = qkbuf[(size_t)s2 * 128 + rN * 16 + 8 + h];
    }
    float logit = qv + klog + a * ch;
    logit = (logit > 0.f) ? logit : NEG * logit;
    float p;
    if (logit <= m) {
      p = __expf(logit - m);
    } else {
      const float sc = __expf(m - logit);
      l *= sc;
#pragma unroll
      for (int c = 0; c < 8; ++c) acc[c] *= sc;
      m = logit;
      p = 1.f;
    }
    l += p;
    acc[0] = fmaf(p, __uint_as_float((tv.x & 0xffffu) << 16), acc[0]);
    acc[1] = fmaf(p, __uint_as_float(tv.x & 0xffff0000u), acc[1]);
    acc[2] = fmaf(p, __uint_as_float((tv.y & 0xffffu) << 16), acc[2]);
    acc[3] = fmaf(p, __uint_as_float(tv.y & 0xffff0000u), acc[3]);
    acc[4] = fmaf(p, __uint_as_float((tv.z & 0xffffu) << 16), acc[4]);
    acc[5] = fmaf(p, __uint_as_float(tv.z & 0xffff0000u), acc[5]);
    acc[6] = fmaf(p, __uint_as_float((tv.w & 0xffffu) << 16), acc[6]);
    acc[7] = fmaf(p, __uint_as_float(tv.w & 0xffff0000u), acc[7]);
  }
  const float inv = 1.f / (l + 1e-16f);
  __shared__ float sm[4][HD];
#pragma unroll
  for (int c = 0; c < 8; ++c) sm[wv][c0 + c] = acc[c] * inv;
  __syncthreads();
  const int d = lane;
  float s = 0.f;
#pragma unroll
  for (int hh = 0; hh < NHEAD; ++hh) s += sm[wv][hh * 64 + d];
  out[(size_t)n * DOUT + d] = s * 0.125f + bias[d];
}

// ---------- launch ----------
extern "C" void kernel_launch(void* const* d_in, const int* in_sizes, int n_in,
                              void* d_out, int out_size, void* d_ws, size_t ws_size,
                              hipStream_t stream) {
  const float* x   = (const float*)d_in[0];
  const int*   ei  = (const int*)d_in[1];
  const int*   et  = (const int*)d_in[2];
  const float* ea  = (const float*)d_in[3];
  const float* W1  = (const float*)d_in[4];
  const float* q1  = (const float*)d_in[5];
  const float* k1  = (const float*)d_in[6];
  const float* We1 = (const float*)d_in[7];
  const float* e1  = (const float*)d_in[8];
  const float* b1  = (const float*)d_in[9];
  const float* W2  = (const float*)d_in[10];
  const float* q2  = (const float*)d_in[11];
  const float* k2  = (const float*)d_in[12];
  const float* We2 = (const float*)d_in[13];
  const float* e2  = (const float*)d_in[14];
  const float* b2  = (const float*)d_in[15];
  float* out = (float*)d_out;

  char* w = (char*)d_ws;
  auto alloc = [&](size_t bytes) {
    char* p = w;
    w += (bytes + 255) & ~(size_t)255;
    return p;
  };
  float* qkbuf  = (float*)alloc((size_t)NN * 128 * 4);
  unsigned short* WQKT = (unsigned short*)alloc((size_t)256 * HD * 2);
  unsigned short* A2 = (unsigned short*)alloc((size_t)MPAD * HD * 2);
  unsigned short* BT = (unsigned short*)alloc((size_t)RREL * HD * HD * 2);
  float* cvec1  = (float*)alloc(64);
  float* cvec2  = (float*)alloc(64);
  int*   meta   = (int*)alloc(64);
  int*   deg    = (int*)alloc((size_t)NN * 4);
  int*   rowptr = (int*)alloc((size_t)(NN + 1) * 4);
  int*   fill   = (int*)alloc((size_t)NN * 4);
  int*   csr_src= (int*)alloc((size_t)ETOT * 4);
  int*   csr_et = (int*)alloc((size_t)ETOT * 4);
  float* csr_ea = (float*)alloc((size_t)ETOT * 4);
  unsigned short* t = (unsigned short*)alloc((size_t)RREL * MPAD * HD * 2);
  (void)ws_size;

  (void)hipMemsetAsync(meta, 0, 4, stream);
  (void)hipMemsetAsync(deg, 0, (size_t)NN * 4, stream);
  // A: hist | asplit | wqk1 | bsplit1
  k_prep1<<<NBH + NBA + NBW1 + NBB1, 256, 0, stream>>>(
      ei, et, deg, meta, x, A2, W1, q1, k1, We1, e1, WQKT, cvec1, BT);
  k_scan<<<1, 1024, 0, stream>>>(deg, rowptr, fill);
  // layer 1 GEMM (Kp=256) + qk tail + scatter tail
  k_mgemm<<<NMAIN + NQK + NSCAT, 512, 0, stream>>>(
      A2, BT, WQKT, t, qkbuf, 256, ei, et, ea, meta, fill,
      csr_src, csr_et, csr_ea);
  // D: attn1 (writes A2, stride 512) | bsplit2 | wqk2
  k_attn1f<<<NBATT + NBB2 + NBW2, 256, 0, stream>>>(
      t, qkbuf, cvec1, rowptr, csr_src, csr_et, csr_ea, b1, A2,
      W2, q2, k2, We2, e2, WQKT, cvec2, BT);
  // layer 2 GEMM (Kp=512) + qk tail (no scatter)
  k_mgemm<<<NMAIN + NQK, 512, 0, stream>>>(
      A2, BT, WQKT, t, qkbuf, 512, ei, et, ea, meta, fill,
      csr_src, csr_et, csr_ea);
  k_attn0<<<NN / 4, 256, 0, stream>>>(t, qkbuf, cvec2, rowptr, csr_src, csr_et,
                                      csr_ea, b2, out);
}